// Round 5
// baseline (646.627 us; speedup 1.0000x reference)
//
#include <hip/hip_runtime.h>
#include <hip/hip_bf16.h>
#include <cstdint>
#include <cstddef>

#define T_SEQ 4096
#define HID   2048
#define NH    16
#define HD    128
#define QKVN  6144
#define KVB   32

typedef unsigned short u16;
typedef __bf16 bf16x8 __attribute__((ext_vector_type(8)));
typedef float  f32x4  __attribute__((ext_vector_type(4)));

typedef const __attribute__((address_space(1))) void* gas_ptr;
typedef __attribute__((address_space(3))) void* las_ptr;

__device__ __forceinline__ void async16(const void* g, void* l) {
  __builtin_amdgcn_global_load_lds((gas_ptr)g, (las_ptr)l, 16, 0, 0);
}

__device__ __forceinline__ u16 f2bf(float f) {
  unsigned int u = __float_as_uint(f);
  u += 0x7fffu + ((u >> 16) & 1u);
  return (u16)(u >> 16);
}

// ---------------- elementwise cast f32 -> bf16 ----------------
__global__ void cast_f32_bf16(const float* __restrict__ in, u16* __restrict__ out, int n) {
  int i = (blockIdx.x * blockDim.x + threadIdx.x) * 4;
  if (i >= n) return;
  float4 v = *(const float4*)&in[i];
  uint2 o;
  o.x = (unsigned)f2bf(v.x) | ((unsigned)f2bf(v.y) << 16);
  o.y = (unsigned)f2bf(v.z) | ((unsigned)f2bf(v.w) << 16);
  *(uint2*)&out[i] = o;
}

// ---------------- transpose + cast: f32 [R][C] -> bf16 [C][R] ----------------
__global__ void transpose_cast(const float* __restrict__ in, u16* __restrict__ out,
                               int R, int C) {
  __shared__ float tile[64][65];
  int c0 = blockIdx.x * 64, r0 = blockIdx.y * 64;
  int tid = threadIdx.x;
#pragma unroll
  for (int i = 0; i < 16; ++i) {
    int e = i * 256 + tid;
    int rr = e >> 6, cc = e & 63;
    tile[rr][cc] = in[(size_t)(r0 + rr) * C + c0 + cc];
  }
  __syncthreads();
#pragma unroll
  for (int i = 0; i < 16; ++i) {
    int e = i * 256 + tid;
    int oc = e >> 6, orr = e & 63;
    out[(size_t)(c0 + oc) * R + r0 + orr] = f2bf(tile[orr][oc]);
  }
}

// ---------------- GEMM: C[M][N] = A[M][K] * BT[N][K]^T  (bf16 in, f32 out) --------
// 128x128 tile, BK=32, double-buffered staging.
__global__ __launch_bounds__(256)
void gemm_bf16_bt(const u16* __restrict__ A, const u16* __restrict__ BT,
                  float* __restrict__ C, int M, int N, int K) {
  __shared__ u16 As[2][128 * 32];
  __shared__ u16 Bs[2][128 * 32];
  int tid = threadIdx.x;
  int row0 = blockIdx.y * 128, col0 = blockIdx.x * 128;
  int wv = tid >> 6, lane = tid & 63, lr = lane & 15, lq = lane >> 4;
  int wm = (wv >> 1) * 64, wn = (wv & 1) * 64;
  f32x4 acc[4][4] = {};

  auto stage = [&](int buf, int ks) {
#pragma unroll
    for (int k = 0; k < 2; ++k) {
      int c = k * 256 + tid;            // 512 chunks per matrix, dest lane-linear
      int row = c >> 2, col = c & 3;
      async16(&A[(size_t)(row0 + row) * K + ks + col * 8], &As[buf][c * 8]);
      async16(&BT[(size_t)(col0 + row) * K + ks + col * 8], &Bs[buf][c * 8]);
    }
  };

  stage(0, 0);
  __syncthreads();
  int nk = K >> 5;
  for (int t = 0; t < nk; ++t) {
    int cur = t & 1;
    if (t + 1 < nk) stage(cur ^ 1, (t + 1) * 32);

    bf16x8 a[4], b[4];
#pragma unroll
    for (int mi = 0; mi < 4; ++mi)
      a[mi] = *(const bf16x8*)&As[cur][(wm + mi * 16 + lr) * 32 + lq * 8];
#pragma unroll
    for (int ni = 0; ni < 4; ++ni)
      b[ni] = *(const bf16x8*)&Bs[cur][(wn + ni * 16 + lr) * 32 + lq * 8];
#pragma unroll
    for (int mi = 0; mi < 4; ++mi)
#pragma unroll
      for (int ni = 0; ni < 4; ++ni)
        acc[mi][ni] = __builtin_amdgcn_mfma_f32_16x16x32_bf16(a[mi], b[ni], acc[mi][ni], 0, 0, 0);
    __syncthreads();
  }

#pragma unroll
  for (int mi = 0; mi < 4; ++mi)
#pragma unroll
    for (int ni = 0; ni < 4; ++ni)
#pragma unroll
      for (int r = 0; r < 4; ++r)
        C[(size_t)(row0 + wm + mi * 16 + lq * 4 + r) * N + col0 + wn + ni * 16 + lr] =
            acc[mi][ni][r];
}

// ---------------- RoPE + head-major reorg for Q,K ----------------
// Q additionally pre-scaled by (1/sqrt(HD)) * log2(e) so softmax uses exp2 directly.
#define SCL2 0.12753224f

__global__ void rope_reorg(const float* __restrict__ qkv, const int* __restrict__ pos,
                           u16* __restrict__ Qh, u16* __restrict__ Kh) {
  int idx = blockIdx.x * 256 + threadIdx.x;
  if (idx >= T_SEQ * NH * 64) return;
  int d = idx & 63;
  int h = (idx >> 6) & (NH - 1);
  int t = idx >> 10;
  float p = (float)pos[t];
  float inv = exp2f((float)d * -0.20762050594046932f);
  float f = p * inv;
  float s, c;
  __sincosf(f, &s, &c);

  size_t ib = (size_t)t * QKVN + h * HD + d;
  float q1 = qkv[ib], q2 = qkv[ib + 64];
  float k1 = qkv[ib + HID], k2 = qkv[ib + HID + 64];
  size_t ob = ((size_t)h * T_SEQ + t) * HD + d;
  Qh[ob]      = f2bf((q1 * c - q2 * s) * SCL2);
  Qh[ob + 64] = f2bf((q2 * c + q1 * s) * SCL2);
  Kh[ob]      = f2bf(k1 * c - k2 * s);
  Kh[ob + 64] = f2bf(k2 * c + k1 * s);
}

// ---------------- V transpose: qkv v-part f32 -> Vt bf16 [NH][HD][T] -------------
__global__ void vtrans(const float* __restrict__ qkv, u16* __restrict__ Vt) {
  __shared__ float tile[64][129];
  int t0 = blockIdx.x * 64;
  int h = blockIdx.y;
  int tid = threadIdx.x;
#pragma unroll
  for (int i = 0; i < 32; ++i) {
    int e = i * 256 + tid;
    int tt = e >> 7, d = e & 127;
    tile[tt][d] = qkv[(size_t)(t0 + tt) * QKVN + 2 * HID + h * HD + d];
  }
  __syncthreads();
#pragma unroll
  for (int i = 0; i < 32; ++i) {
    int e = i * 256 + tid;
    int d = e >> 6, tt = e & 63;
    Vt[((size_t)h * HD + d) * T_SEQ + t0 + tt] = f2bf(tile[tt][d]);
  }
}

// ---------------- causal flash attention v5 -------------------------------------
// 2 waves/block (Q-tile 64, 32 rows/wave), KVBLK=32, dbuf staging, 1024 blocks
// (4/CU), balanced bq decode. K XOR-8 swizzle; V XOR key (row&3)^((row>>2)&3)
// (2-way residual = free); P padded 72B rows (VALU-written, so padding is legal).
__global__ __launch_bounds__(128)
void attn_fwd(const u16* __restrict__ Qh, const u16* __restrict__ Kh,
              const u16* __restrict__ Vt, u16* __restrict__ attn) {
  __shared__ u16 Ks[2][32 * 128];   // [kv][d] 256B rows, XOR-8 swizzle
  __shared__ u16 Vs[2][128 * 32];   // [d][kv] 64B rows, XOR key swizzle
  __shared__ u16 Ps[2][32 * 36];    // per-wave [q][kv], 72B padded rows

  int tid = threadIdx.x;
  int wv = tid >> 6, lane = tid & 63, lr = lane & 15, lq = lane >> 4;
  // balanced decode: 4 co-resident quadrant blocks get bq {gs,31-gs,32+gs,63-gs}
  int id = blockIdx.x;
  int g = id & 255, quad = id >> 8;
  int h = g >> 4, gs = g & 15;
  int bq = (quad == 0) ? gs : (quad == 1) ? (31 - gs) : (quad == 2) ? (32 + gs) : (63 - gs);
  int q0 = bq * 64, wrow0 = q0 + wv * 32;
  char* PsB = (char*)&Ps[wv][0];

  // Q fragments (pre-scaled): rows wrow0 + mi*16 + lr, k = kd*32 + lq*8
  bf16x8 qf[2][4];
#pragma unroll
  for (int mi = 0; mi < 2; ++mi)
#pragma unroll
    for (int kd = 0; kd < 4; ++kd)
      qf[mi][kd] = *(const bf16x8*)
          &Qh[((size_t)h * T_SEQ + wrow0 + mi * 16 + lr) * HD + kd * 32 + lq * 8];

  f32x4 acc_o[2][8] = {};
  float m_run[2][4], l_run[2][4];
#pragma unroll
  for (int mi = 0; mi < 2; ++mi)
#pragma unroll
    for (int r = 0; r < 4; ++r) { m_run[mi][r] = -1e30f; l_run[mi][r] = 0.0f; }

  auto stage = [&](int buf, int jb) {
#pragma unroll
    for (int k = 0; k < 4; ++k) {      // K tile: 512 chunks, 16/row, src pre-swz
      int c = k * 128 + tid;
      int row = c >> 4;
      int sc = (c ^ (row & 7)) & 15;
      async16(&Kh[((size_t)h * T_SEQ + jb + row) * HD + sc * 8], &Ks[buf][c * 8]);
    }
#pragma unroll
    for (int k = 0; k < 4; ++k) {      // V tile: 512 chunks, 4/row, key-swz
      int c = k * 128 + tid;
      int row = c >> 2, col = c & 3;
      int key = (row & 3) ^ ((row >> 2) & 3);
      async16(&Vt[((size_t)h * HD + row) * T_SEQ + jb + (col ^ key) * 8],
              &Vs[buf][c * 8]);
    }
  };

  int nt = bq * 2 + 2;
  stage(0, 0);
  __syncthreads();

  for (int j = 0; j < nt; ++j) {
    int cur = j & 1;
    int jb = j * KVB;
    if (j + 1 < nt) stage(cur ^ 1, jb + KVB);

    if (jb <= wrow0 + 31) {
      const char* KsB = (const char*)&Ks[cur][0];
      const char* VsB = (const char*)&Vs[cur][0];

      // ---- S = Q K^T  (32 x 32) ----
      f32x4 s_acc[2][2] = {};
#pragma unroll
      for (int kd = 0; kd < 4; ++kd) {
#pragma unroll
        for (int nj = 0; nj < 2; ++nj) {
          int row = nj * 16 + lr;
          int byt = (row << 8) + kd * 64 + lq * 16;
          bf16x8 kf = *(const bf16x8*)(KsB + (byt ^ ((row & 7) << 4)));
#pragma unroll
          for (int mi = 0; mi < 2; ++mi)
            s_acc[mi][nj] = __builtin_amdgcn_mfma_f32_16x16x32_bf16(
                qf[mi][kd], kf, s_acc[mi][nj], 0, 0, 0);
        }
      }

      bool diag = (jb + KVB - 1 > wrow0);
      // ---- online softmax (l kept as per-lane partial) ----
#pragma unroll
      for (int mi = 0; mi < 2; ++mi) {
        float pm[4];
#pragma unroll
        for (int r = 0; r < 4; ++r) {
          int qrow = wrow0 + mi * 16 + lq * 4 + r;
          float mx = -1e30f;
#pragma unroll
          for (int nj = 0; nj < 2; ++nj) {
            float s = s_acc[mi][nj][r];
            if (diag && (jb + nj * 16 + lr > qrow)) s = -1e30f;
            s_acc[mi][nj][r] = s;
            mx = fmaxf(mx, s);
          }
          pm[r] = mx;
        }
#pragma unroll
        for (int r = 0; r < 4; ++r) {
          pm[r] = fmaxf(pm[r], __shfl_xor(pm[r], 1));
          pm[r] = fmaxf(pm[r], __shfl_xor(pm[r], 2));
          pm[r] = fmaxf(pm[r], __shfl_xor(pm[r], 4));
          pm[r] = fmaxf(pm[r], __shfl_xor(pm[r], 8));
        }
#pragma unroll
        for (int r = 0; r < 4; ++r) {
          float mnew = fmaxf(m_run[mi][r], pm[r]);
          float sf = exp2f(m_run[mi][r] - mnew);
          m_run[mi][r] = mnew;
          int prow = mi * 16 + lq * 4 + r;
          float rs = 0.0f;
#pragma unroll
          for (int nj = 0; nj < 2; ++nj) {
            float p = exp2f(s_acc[mi][nj][r] - mnew);
            rs += p;
            *(u16*)(PsB + prow * 72 + (nj * 16 + lr) * 2) = f2bf(p);
          }
          l_run[mi][r] = l_run[mi][r] * sf + rs;   // per-lane partial
#pragma unroll
          for (int nd = 0; nd < 8; ++nd) acc_o[mi][nd][r] *= sf;
        }
      }

      // ---- O += P V  (32 x 128, K=32) ----
#pragma unroll
      for (int mi = 0; mi < 2; ++mi) {
        bf16x8 pa = *(const bf16x8*)(PsB + (mi * 16 + lr) * 72 + lq * 16);
#pragma unroll
        for (int nd = 0; nd < 8; ++nd) {
          int vrow = nd * 16 + lr;
          int key = (vrow & 3) ^ ((vrow >> 2) & 3);
          bf16x8 vb = *(const bf16x8*)(VsB + vrow * 64 + ((lq ^ key) << 4));
          acc_o[mi][nd] = __builtin_amdgcn_mfma_f32_16x16x32_bf16(
              pa, vb, acc_o[mi][nd], 0, 0, 0);
        }
      }
    }
    __syncthreads();
  }

  // epilogue: final l reduction + store
#pragma unroll
  for (int mi = 0; mi < 2; ++mi)
#pragma unroll
    for (int r = 0; r < 4; ++r) {
      float l = l_run[mi][r];
      l += __shfl_xor(l, 1);
      l += __shfl_xor(l, 2);
      l += __shfl_xor(l, 4);
      l += __shfl_xor(l, 8);
      float rl = 1.0f / l;
      int qrow = wrow0 + mi * 16 + lq * 4 + r;
#pragma unroll
      for (int nd = 0; nd < 8; ++nd)
        attn[(size_t)qrow * HID + h * HD + nd * 16 + lr] = f2bf(acc_o[mi][nd][r] * rl);
    }
}

extern "C" void kernel_launch(void* const* d_in, const int* in_sizes, int n_in,
                              void* d_out, int out_size, void* d_ws, size_t ws_size,
                              hipStream_t stream) {
  const float* hidden    = (const float*)d_in[0];
  const int*   positions = (const int*)d_in[1];
  const float* w_qkv     = (const float*)d_in[2];
  const float* w_o       = (const float*)d_in[3];
  float* out = (float*)d_out;

  char* p = (char*)d_ws;
  u16* hs_b   = (u16*)p;  p += (size_t)T_SEQ * HID * 2;
  u16* wqkvT  = (u16*)p;  p += (size_t)QKVN * HID * 2;
  u16* woT    = (u16*)p;  p += (size_t)HID * HID * 2;
  float* qkvf = (float*)p; p += (size_t)T_SEQ * QKVN * 4;
  u16* Qh     = (u16*)p;  p += (size_t)T_SEQ * HID * 2;
  u16* Kh     = (u16*)p;  p += (size_t)T_SEQ * HID * 2;
  u16* Vt     = (u16*)p;  p += (size_t)T_SEQ * HID * 2;
  u16* attn_b = (u16*)p;  p += (size_t)T_SEQ * HID * 2;

  cast_f32_bf16<<<(T_SEQ * HID / 4 + 255) / 256, 256, 0, stream>>>(hidden, hs_b, T_SEQ * HID);
  transpose_cast<<<dim3(QKVN / 64, HID / 64), 256, 0, stream>>>(w_qkv, wqkvT, HID, QKVN);
  transpose_cast<<<dim3(HID / 64, HID / 64), 256, 0, stream>>>(w_o, woT, HID, HID);
  gemm_bf16_bt<<<dim3(QKVN / 128, T_SEQ / 128), 256, 0, stream>>>(hs_b, wqkvT, qkvf,
                                                                  T_SEQ, QKVN, HID);
  rope_reorg<<<(T_SEQ * NH * 64 + 255) / 256, 256, 0, stream>>>(qkvf, positions, Qh, Kh);
  vtrans<<<dim3(T_SEQ / 64, NH), 256, 0, stream>>>(qkvf, Vt);
  attn_fwd<<<1024, 128, 0, stream>>>(Qh, Kh, Vt, attn_b);
  gemm_bf16_bt<<<dim3(HID / 128, T_SEQ / 128), 256, 0, stream>>>(attn_b, woT, out,
                                                                 T_SEQ, HID, HID);
}